// Round 8
// baseline (70.683 us; speedup 1.0000x reference)
//
#include <hip/hip_runtime.h>
#include <stdint.h>

// ============================================================================
// MoE collapses exactly to: out = relu(x @ w1) @ w2   (round-0 analysis)
//   - shared expert weights => both top-2 slots compute identical f(x[s])
//   - g1+g2 normalized to 1 => combine gather returns f(x[s])
//   - capacity = S and count1+count2 <= S => no token dropped
// Wg is unused.
//
// Round-7 -> 8:
//  * GEMM: port m201's 2-barrier-per-phase role-split schedule to the
//    verified 128x256 / 256-block / 3-buffer geometry. K-step = 2 phases:
//    {8 ds_read + stage part; s_barrier; lgkmcnt(0); setprio MFMA x8;
//     s_barrier}. vmcnt(6) before the trailing barrier of phase 1 =
//    residency barrier for tile t+1 (never vmcnt(0) mid-loop).
//  * prep: vectorized 64x64 float4/ushort4 transposes (was scalar f32).
// ============================================================================

typedef __attribute__((ext_vector_type(4))) float f32x4;
typedef __attribute__((ext_vector_type(16))) float f32x16;
typedef __attribute__((ext_vector_type(8))) short bf16x8;

#define GPTR(p) (const __attribute__((address_space(1))) void*)(p)
#define LPTR(p) (__attribute__((address_space(3))) void*)(p)

__device__ __forceinline__ ushort f2bf(float f) {
  uint32_t u = __float_as_uint(f);
  uint32_t r = (u + 0x7FFFu + ((u >> 16) & 1u)) >> 16;  // RNE
  return (ushort)r;
}
__device__ __forceinline__ float bf2f(ushort u) {
  return __uint_as_float((uint32_t)u << 16);
}

// ---- fused prep: x->bf16 cvt + vectorized 64x64 transposes ------------------
// grid: [0,2048) cvt x (float4); [2048,3072) w1 -> w1t; [3072,4096) w2 -> w2t
__global__ __launch_bounds__(256) void prep(const float* __restrict__ x,
                                            const float* __restrict__ w1,
                                            const float* __restrict__ w2,
                                            ushort* __restrict__ xb,
                                            ushort* __restrict__ w1t,
                                            ushort* __restrict__ w2t) {
  const int b = blockIdx.x, tid = threadIdx.x;
  if (b < 2048) {  // cvt: 2048 blocks x 256 th x float4 = 2M elems
    int i = b * 256 + tid;
    float4 v = ((const float4*)x)[i];
    ushort4 o;
    o.x = f2bf(v.x); o.y = f2bf(v.y); o.z = f2bf(v.z); o.w = f2bf(v.w);
    ((ushort4*)xb)[i] = o;
    return;
  }
  const float* in;
  ushort* outp;
  int R, C, bt;
  if (b < 3072) { bt = b - 2048; in = w1; outp = w1t; R = 1024; C = 4096; }
  else          { bt = b - 3072; in = w2; outp = w2t; R = 4096; C = 1024; }
  const int ntx = C / 64;
  const int bx = bt % ntx, by = bt / ntx;
  const int c0 = bx * 64, r0 = by * 64;
  __shared__ float tile[64][65];
  const int tx = tid & 15, ty = tid >> 4;  // 16 x 16
#pragma unroll
  for (int rr = 0; rr < 64; rr += 16) {
    float4 v = *(const float4*)&in[(size_t)(r0 + ty + rr) * C + c0 + tx * 4];
    tile[ty + rr][tx * 4 + 0] = v.x;
    tile[ty + rr][tx * 4 + 1] = v.y;
    tile[ty + rr][tx * 4 + 2] = v.z;
    tile[ty + rr][tx * 4 + 3] = v.w;
  }
  __syncthreads();
#pragma unroll
  for (int cc = 0; cc < 64; cc += 16) {
    const int c = ty + cc;   // output row (= original col)
    const int r = tx * 4;    // 4 consecutive original rows
    ushort4 o;
    o.x = f2bf(tile[r + 0][c]);
    o.y = f2bf(tile[r + 1][c]);
    o.z = f2bf(tile[r + 2][c]);
    o.w = f2bf(tile[r + 3][c]);
    *(ushort4*)&outp[(size_t)(c0 + c) * R + r0 + r] = o;
  }
}

// ---- out += sum of 3 bf16 partials -----------------------------------------
__global__ void reduce_out(float* __restrict__ out, const ushort* __restrict__ pb,
                           int SD) {
  int i = blockIdx.x * blockDim.x + threadIdx.x;  // 4 floats / thread
  if (i >= SD / 4) return;
  f32x4 a = ((const f32x4*)out)[i];
#pragma unroll
  for (int j = 0; j < 3; ++j) {
    ushort4 u = ((const ushort4*)(pb + (size_t)j * SD))[i];
    a[0] += bf2f(u.x); a[1] += bf2f(u.y); a[2] += bf2f(u.z); a[3] += bf2f(u.w);
  }
  ((f32x4*)out)[i] = a;
}

// ---- bf16 GEMM, B transposed ([N][K]); 2-phase role-split schedule ----------
// MODE 1: C0 = relu(A@Bt^T) as bf16.  MODE 2: split-K; bz==0 -> fp32 C0,
// bz>0 -> bf16 partial C1 + (bz-1)*M*N.
// BM=128 x BN=256 x BK=64, 8 waves (2x4), per-wave 64x64 (2x2 32x32 frags).
// 3-buffer LDS (144 KB), depth-2 prefetch, steady-state vmcnt(6).
template <int MODE>
__global__ __launch_bounds__(512) void gemm_pipe(const ushort* __restrict__ A,
                                                 const ushort* __restrict__ Bt,
                                                 void* __restrict__ C0,
                                                 void* __restrict__ C1,
                                                 int M, int N, int Ks, int Ktot,
                                                 int ncx, int cpz) {
  constexpr int BM = 128, BN = 256, BK = 64;
  __shared__ ushort As[3][BM * BK];  // 3 x 16 KB
  __shared__ ushort Bs[3][BN * BK];  // 3 x 32 KB   (total 144 KB)

  const int tid = threadIdx.x;
  const int lane = tid & 63, wid = tid >> 6;  // 8 waves
  const int wr = wid >> 2, wc = wid & 3;      // 2 x 4 wave grid

  // T1 (2D-chunked): chunk (=XCD) = blockIdx.x & 7, 32 blocks/chunk -> 4x8.
  const int ck = blockIdx.x & 7;
  const int w = blockIdx.x >> 3;
  const int bz = ck / cpz;
  const int rem = ck % cpz;
  const int bx = (rem % ncx) * 4 + (w & 3);
  const int by = (rem / ncx) * 8 + (w >> 2);
  const int row0 = by * BM, col0 = bx * BN;
  const int kbase = bz * Ks;

  f32x16 acc[2][2];
#pragma unroll
  for (int m = 0; m < 2; ++m)
#pragma unroll
    for (int n = 0; n < 2; ++n) acc[m][n] = (f32x16)(0.f);

  // staging: 6 global_load_lds x 16B per thread (A 2 issues + B 4 issues).
  // LDS dest LINEAR; source col XOR-swizzled (rule #21, verified r4-r7).
  const int rA = tid >> 3;        // 0..63 row within an 8KB issue
  const int cb = (tid & 7) * 16;  // byte col within 128B row
  // part p: 0 -> A issues {0,1}; 1 -> B issues {0,1}; 2 -> B issues {2,3}
  auto stage_part = [&](int buf, int k0, int p) {
    if (p == 0) {
#pragma unroll
      for (int i = 0; i < 2; ++i) {
        int r = i * 64 + rA;
        int csw = cb ^ ((r & 7) << 4);
        __builtin_amdgcn_global_load_lds(
            GPTR((const char*)(A + (size_t)(row0 + r) * Ktot + k0) + csw),
            LPTR((char*)&As[buf][0] + i * 8192 + wid * 1024), 16, 0, 0);
      }
    } else {
#pragma unroll
      for (int j2 = 0; j2 < 2; ++j2) {
        int j = (p - 1) * 2 + j2;
        int r = j * 64 + rA;
        int csw = cb ^ ((r & 7) << 4);
        __builtin_amdgcn_global_load_lds(
            GPTR((const char*)(Bt + (size_t)(col0 + r) * Ktot + k0) + csw),
            LPTR((char*)&Bs[buf][0] + j * 8192 + wid * 1024), 16, 0, 0);
      }
    }
  };

  const int nt = Ks / BK;  // 16 for both GEMMs
  stage_part(0, kbase, 0); stage_part(0, kbase, 1); stage_part(0, kbase, 2);
  stage_part(1, kbase + BK, 0); stage_part(1, kbase + BK, 1); stage_part(1, kbase + BK, 2);
  asm volatile("s_waitcnt vmcnt(6)" ::: "memory");
  __builtin_amdgcn_sched_barrier(0);
  __builtin_amdgcn_s_barrier();  // tile 0 resident for all waves
  __builtin_amdgcn_sched_barrier(0);

  for (int t = 0; t < nt; ++t) {
    const ushort* Ab = As[t % 3];
    const ushort* Bb = Bs[t % 3];
    const bool pf = (t + 2 < nt);
    const int knext = kbase + (t + 2) * BK;
    const int pbuf = (t + 2) % 3;

#pragma unroll
    for (int p = 0; p < 2; ++p) {
      // ---- phase p: ds-read 2 k-slices + issue staging part(s) ----
      bf16x8 a2[2][2], b2[2][2];
#pragma unroll
      for (int sl = 0; sl < 2; ++sl) {
        const int s = p * 2 + sl;
        const int kb2 = s * 32 + (lane >> 5) * 16;
#pragma unroll
        for (int m = 0; m < 2; ++m) {
          int R = wr * 64 + m * 32 + (lane & 31);
          a2[sl][m] = *(const bf16x8*)((const char*)Ab + R * 128 + (kb2 ^ ((R & 7) << 4)));
        }
#pragma unroll
        for (int n = 0; n < 2; ++n) {
          int R = wc * 64 + n * 32 + (lane & 31);
          b2[sl][n] = *(const bf16x8*)((const char*)Bb + R * 128 + (kb2 ^ ((R & 7) << 4)));
        }
      }
      if (pf) {
        if (p == 0) { stage_part(pbuf, knext, 0); stage_part(pbuf, knext, 1); }
        else        { stage_part(pbuf, knext, 2); }
      }
      __builtin_amdgcn_sched_barrier(0);
      __builtin_amdgcn_s_barrier();  // all waves issued their reads
      asm volatile("s_waitcnt lgkmcnt(0)" ::: "memory");
      __builtin_amdgcn_sched_barrier(0);  // rule 18: fence MFMA after lgkm wait
      __builtin_amdgcn_s_setprio(1);
#pragma unroll
      for (int sl = 0; sl < 2; ++sl)
#pragma unroll
        for (int m = 0; m < 2; ++m)
#pragma unroll
          for (int n = 0; n < 2; ++n)
            acc[m][n] = __builtin_amdgcn_mfma_f32_32x32x16_bf16(a2[sl][m], b2[sl][n],
                                                                acc[m][n], 0, 0, 0);
      __builtin_amdgcn_s_setprio(0);
      __builtin_amdgcn_sched_barrier(0);
      if (p == 1 && t < nt - 1) {
        // residency wait for tile t+1 BEFORE the trailing barrier:
        // outstanding = tile t+1 (6, possibly landed) + tile t+2 (6 if staged)
        if (t + 2 < nt) asm volatile("s_waitcnt vmcnt(6)" ::: "memory");
        else            asm volatile("s_waitcnt vmcnt(0)" ::: "memory");
        __builtin_amdgcn_sched_barrier(0);
      }
      __builtin_amdgcn_s_barrier();  // phase boundary / next-tile residency
      __builtin_amdgcn_sched_barrier(0);
    }
  }

  // epilogue; 32x32 C/D layout (m74/m101-verified):
  //   col = lane&31, row = (r&3) + 8*(r>>2) + 4*(lane>>5)
  const int rbase = row0 + wr * 64, cbase = col0 + wc * 64;
#pragma unroll
  for (int m = 0; m < 2; ++m) {
#pragma unroll
    for (int n = 0; n < 2; ++n) {
      const int col = cbase + n * 32 + (lane & 31);
#pragma unroll
      for (int r = 0; r < 16; ++r) {
        const int row = rbase + m * 32 + (r & 3) + 8 * (r >> 2) + 4 * (lane >> 5);
        float v = acc[m][n][r];
        size_t idx = (size_t)row * N + col;
        if (MODE == 1) {
          v = v > 0.f ? v : 0.f;
          ((ushort*)C0)[idx] = f2bf(v);
        } else {
          if (bz == 0)
            ((float*)C0)[idx] = v;
          else
            ((ushort*)C1)[(size_t)(bz - 1) * M * N + idx] = f2bf(v);
        }
      }
    }
  }
}

extern "C" void kernel_launch(void* const* d_in, const int* in_sizes, int n_in,
                              void* d_out, int out_size, void* d_ws, size_t ws_size,
                              hipStream_t stream) {
  const float* x  = (const float*)d_in[0];
  // d_in[1] (Wg) is provably unused: gating collapses to identity (see header)
  const float* w1 = (const float*)d_in[2];
  const float* w2 = (const float*)d_in[3];
  float* out = (float*)d_out;

  constexpr int S = 2048, D = 1024, F = 4096;
  char* ws = (char*)d_ws;
  ushort* xb  = (ushort*)(ws);                                    // [S][D]  4 MB
  ushort* w1t = (ushort*)(ws + (size_t)S * D * 2);                // [F][D]  8 MB
  ushort* w2t = (ushort*)(ws + (size_t)(S * D + F * D) * 2);      // [D][F]  8 MB
  ushort* H   = (ushort*)(ws + (size_t)(S * D + 2 * F * D) * 2);  // [S][F] 16 MB
  // 3 bf16 split-K partials (12 MB) overlay xb+w1t (dead after GEMM1).
  ushort* pb = (ushort*)(ws);

  // fused prep: 2048 cvt + 1024 w1-transpose + 1024 w2-transpose (64x64 tiles)
  hipLaunchKernelGGL(prep, dim3(4096), dim3(256), 0, stream,
                     x, w1, w2, xb, w1t, w2t);
  // GEMM1: H = relu(xb @ w1t^T)  [2048 x 4096], K=1024
  //   grid 16x16 = 256; chunks: ncx=4, cpz=8 (nz=1)
  hipLaunchKernelGGL((gemm_pipe<1>), dim3(256), dim3(512), 0, stream,
                     xb, w1t, (void*)H, nullptr, S, F, D, D, 4, 8);
  // GEMM2: out = H @ w2t^T  [2048 x 1024], K=4096 split 4x1024
  //   grid 4x16x4 = 256; chunks: ncx=1, cpz=2 (nz=4)
  hipLaunchKernelGGL((gemm_pipe<2>), dim3(256), dim3(512), 0, stream,
                     H, w2t, (void*)out, (void*)pb, S, D, F / 4, F, 1, 2);
  // out += p1 + p2 + p3
  hipLaunchKernelGGL(reduce_out, dim3((S * D / 4 + 255) / 256), dim3(256), 0, stream,
                     out, pb, S * D);
}